// Round 2
// baseline (376.498 us; speedup 1.0000x reference)
//
#include <hip/hip_runtime.h>
#include <math.h>

// ProtoLoss: loss = mean_n( -2*sim[n,fam[n]] + logsumexp_f(4*sim[n,f]) )
// sim = (e.p)/(||e||*||p||) -- scale-invariant in p, so the segment-mean's
// count division cancels: p_hat = raw_sum/||raw_sum||. No counts anywhere.
// N=262144, D=128, F=64.
//
// A) 256 blocks x 1024 thr (16 waves, 4 waves/SIMD). Lane (r=lane&15,
//    c=lane>>4): 16 rows processed SIMULTANEOUSLY per wave, each lane owns
//    32 contiguous dims (8 float4 loads, register-resident). Norm = 2 shfls
//    per 16 rows (was 6 per row). Segment accumulate: ds_add_f32 (via
//    unsafeAtomicAdd) into 4 LDS replicas (132 KB) with a bank-staggered
//    slot mapping slot(f,d)=f*129+32q+(((d&31)+8q)&31), q=d>>5 -- breaks the
//    structural dims=mod32 64-way conflict to ~2-way; value index stays
//    compile-time static (only the address is permuted).
// B1) 256-block reduce of 256 partials -> protoRaw fp32 (natural layout).
// B2) 1-block normalize -> protoB bf16 natural layout.
// C) de-staged MFMA (A from L3-warm ehat, B L1-resident); per-block partial
//    to part[bid] (plain store -- NO same-address atomic drain).
// D) 1-block reduce of 2048 partials -> d_out.

#define D_DIM 128
#define F_NUM 64
#define REP_STRIDE (F_NUM * 129)   // 8256 floats/replica; +1 pad spreads banks by f

typedef __attribute__((ext_vector_type(8))) short short8;
typedef __attribute__((ext_vector_type(4))) float f32x4;

static __device__ __forceinline__ unsigned short f2bf(float x) {
  union { float f; unsigned u; } v; v.f = x;
  unsigned r = v.u + 0x7FFFu + ((v.u >> 16) & 1u);   // RNE
  return (unsigned short)(r >> 16);
}

// ---------------- Pass A -----------------------------------------------------
__global__ __launch_bounds__(1024) void pass_a(
    const float* __restrict__ emb, const int* __restrict__ fam,
    float* __restrict__ psum, unsigned int* __restrict__ ehat)
{
  __shared__ float acc[4 * REP_STRIDE];      // 132096 B
  int t = threadIdx.x;
  for (int i = t; i < 4 * REP_STRIDE; i += 1024) acc[i] = 0.f;
  __syncthreads();

  int w = t >> 6, lane = t & 63;
  int r = lane & 15, c = lane >> 4;          // row-in-batch, dim-quarter
  int offc = c << 3;                          // bank stagger per quarter
  float* my = acc + (w & 3) * REP_STRIDE;
  int rowBase = blockIdx.x * 1024 + w * 64;   // wave owns 64 rows, 4 batches of 16

  #pragma unroll 1
  for (int b = 0; b < 4; ++b) {
    int row = rowBase + b * 16 + r;
    const float4* src = (const float4*)(emb + (size_t)row * D_DIM + c * 32);
    int f = fam[row];                         // 16 distinct dwords, 4x broadcast
    float4 v[8];                              // lane's 32 dims: [c*32, c*32+32)
    #pragma unroll
    for (int i = 0; i < 8; ++i) v[i] = src[i];

    float nq = 0.f;
    #pragma unroll
    for (int i = 0; i < 8; ++i)
      nq += v[i].x * v[i].x + v[i].y * v[i].y + v[i].z * v[i].z + v[i].w * v[i].w;
    nq += __shfl_xor(nq, 16);                 // combine the 4 quarter-lanes
    nq += __shfl_xor(nq, 32);
    float inv = rsqrtf(fmaxf(nq, 1e-20f));

    // ehat row: natural-order bf16 pairs, lane writes its own 64B line
    uint4* dst = (uint4*)(ehat + (size_t)row * 64 + c * 16);
    #pragma unroll
    for (int i = 0; i < 4; ++i) {
      float4 a = v[2 * i], bb = v[2 * i + 1];
      uint4 u;
      u.x = ((unsigned)f2bf(a.y * inv) << 16) | f2bf(a.x * inv);
      u.y = ((unsigned)f2bf(a.w * inv) << 16) | f2bf(a.z * inv);
      u.z = ((unsigned)f2bf(bb.y * inv) << 16) | f2bf(bb.x * inv);
      u.w = ((unsigned)f2bf(bb.w * inv) << 16) | f2bf(bb.z * inv);
      dst[i] = u;
    }

    // segment accumulate RAW values; staggered slots -> ~2-way banks.
    // value index k is compile-time static; only the address is permuted.
    const float* vf = (const float*)v;
    float* fb = my + f * 129 + 32 * c;
    #pragma unroll
    for (int k = 0; k < 32; ++k) {
      int dk = (k + offc) & 31;
      unsafeAtomicAdd(&fb[dk], vf[(dk >> 2) * 4 + (dk & 3)]);
    }
  }
  __syncthreads();

  // merge 4 replicas -> natural-layout psum slot (un-permute slots)
  float* outp = psum + (size_t)blockIdx.x * (F_NUM * D_DIM);
  for (int idx = t; idx < F_NUM * D_DIM; idx += 1024) {
    int f = idx >> 7, d = idx & 127, q = d >> 5, s = d & 31;
    int slot = f * 129 + 32 * q + ((s + 8 * q) & 31);
    outp[idx] = acc[slot] + acc[slot + REP_STRIDE] +
                acc[slot + 2 * REP_STRIDE] + acc[slot + 3 * REP_STRIDE];
  }
}

// ---------------- Pass B1 ----------------------------------------------------
__global__ __launch_bounds__(256) void pass_b1(
    const float* __restrict__ psum, float* __restrict__ protoRaw, int nPart)
{
  __shared__ float red[256];
  int f = blockIdx.x >> 2, qd = blockIdx.x & 3;
  int t = threadIdx.x;
  int d = qd * 32 + (t & 31), p0 = t >> 5;   // 8 partial-groups
  int per = nPart >> 3;
  float s = 0.f;
  #pragma unroll 8
  for (int i = 0; i < per; ++i)
    s += psum[(size_t)(p0 + 8 * i) * (F_NUM * D_DIM) + f * D_DIM + d];
  red[t] = s;
  __syncthreads();
  if (t < 32) {
    float r = 0.f;
    #pragma unroll
    for (int k = 0; k < 8; ++k) r += red[k * 32 + t];
    protoRaw[f * D_DIM + qd * 32 + t] = r;
  }
}

// ---------------- Pass B2 ----------------------------------------------------
// 1 block x 256 thr: thread (f=t>>2, pt=t&3) -> normalize, bf16 natural layout.
__global__ __launch_bounds__(256) void pass_b2(
    const float* __restrict__ protoRaw, unsigned short* __restrict__ protoB)
{
  int t = threadIdx.x, f = t >> 2, pt = t & 3;
  const float4* src = (const float4*)(protoRaw + f * D_DIM + pt * 32);
  float4 v[8];
  float n2 = 0.f;
  #pragma unroll
  for (int i = 0; i < 8; ++i) {
    v[i] = src[i];
    n2 += v[i].x * v[i].x + v[i].y * v[i].y + v[i].z * v[i].z + v[i].w * v[i].w;
  }
  n2 += __shfl_xor(n2, 1);                   // quad = same f
  n2 += __shfl_xor(n2, 2);
  float inv = rsqrtf(fmaxf(n2, 1e-24f));     // zero-family -> p_hat=0 -> sim=0
  ushort4* dst = (ushort4*)(protoB + f * D_DIM + pt * 32);
  #pragma unroll
  for (int i = 0; i < 8; ++i) {
    ushort4 u;
    u.x = f2bf(v[i].x * inv); u.y = f2bf(v[i].y * inv);
    u.z = f2bf(v[i].z * inv); u.w = f2bf(v[i].w * inv);
    dst[i] = u;
  }
}

// ---------------- Pass C -----------------------------------------------------
// N/128 blocks x 256 thr. Tile: 128 rows x 64 fams, K=128, bf16 MFMA 16x16x32.
// A direct from L3-warm ehat, B L1-resident. Per-block partial -> part[bid].
__global__ __launch_bounds__(256) void pass_c(
    const unsigned short* __restrict__ ehat, const int* __restrict__ fam,
    const unsigned short* __restrict__ protoB, float* __restrict__ part)
{
  __shared__ float sWp[4];
  int t = threadIdx.x;
  int R0 = blockIdx.x * 128;
  int w = t >> 6, lane = t & 63, m16 = lane & 15, q = lane >> 4;

  const short8* A16 = (const short8*)ehat;   // 16 chunks of 8 bf16 per row
  const short8* B16 = (const short8*)protoB;

  int frv[2][4];
  #pragma unroll
  for (int rt = 0; rt < 2; ++rt)
    #pragma unroll
    for (int i = 0; i < 4; ++i)
      frv[rt][i] = fam[R0 + w * 32 + rt * 16 + q * 4 + i];

  short8 bfr[4][4];
  #pragma unroll
  for (int ks = 0; ks < 4; ++ks)
    #pragma unroll
    for (int ft = 0; ft < 4; ++ft)
      bfr[ks][ft] = B16[(ft * 16 + m16) * 16 + ks * 4 + q];

  size_t aBase = (size_t)(R0 + w * 32 + m16) * 16 + q;
  f32x4 acc[2][4] = {};
  #pragma unroll
  for (int ks = 0; ks < 4; ++ks) {
    short8 a0 = A16[aBase + ks * 4];         // row w*32+m16
    short8 a1 = A16[aBase + 256 + ks * 4];   // row +16
    acc[0][0] = __builtin_amdgcn_mfma_f32_16x16x32_bf16(a0, bfr[ks][0], acc[0][0], 0, 0, 0);
    acc[0][1] = __builtin_amdgcn_mfma_f32_16x16x32_bf16(a0, bfr[ks][1], acc[0][1], 0, 0, 0);
    acc[0][2] = __builtin_amdgcn_mfma_f32_16x16x32_bf16(a0, bfr[ks][2], acc[0][2], 0, 0, 0);
    acc[0][3] = __builtin_amdgcn_mfma_f32_16x16x32_bf16(a0, bfr[ks][3], acc[0][3], 0, 0, 0);
    acc[1][0] = __builtin_amdgcn_mfma_f32_16x16x32_bf16(a1, bfr[ks][0], acc[1][0], 0, 0, 0);
    acc[1][1] = __builtin_amdgcn_mfma_f32_16x16x32_bf16(a1, bfr[ks][1], acc[1][1], 0, 0, 0);
    acc[1][2] = __builtin_amdgcn_mfma_f32_16x16x32_bf16(a1, bfr[ks][2], acc[1][2], 0, 0, 0);
    acc[1][3] = __builtin_amdgcn_mfma_f32_16x16x32_bf16(a1, bfr[ks][3], acc[1][3], 0, 0, 0);
  }

  // epilogue: D[row= w*32+rt*16+q*4+i][col= ft*16+m16] = acc[rt][ft][i]
  float wp = 0.f;
  #pragma unroll
  for (int rt = 0; rt < 2; ++rt) {
    #pragma unroll
    for (int i = 0; i < 4; ++i) {
      int fr = frv[rt][i], frh = fr >> 4, frl = fr & 15;
      float es = 0.f, ps = 0.f;
      #pragma unroll
      for (int ft = 0; ft < 4; ++ft) {
        float sim = acc[rt][ft][i];
        es += __expf(4.f * sim - 4.f);       // sim in [-1,1] -> arg in [-8,0]
        if (frl == m16 && frh == ft) ps = sim;
      }
      #pragma unroll
      for (int off = 1; off < 16; off <<= 1) {
        es += __shfl_xor(es, off);
        ps += __shfl_xor(ps, off);
      }
      if (m16 == 0) wp += 4.f + __logf(es) - 2.f * ps;
    }
  }
  wp += __shfl_xor(wp, 16);
  wp += __shfl_xor(wp, 32);
  if (lane == 0) sWp[w] = wp;
  __syncthreads();
  if (t == 0) part[blockIdx.x] = sWp[0] + sWp[1] + sWp[2] + sWp[3];
}

// ---------------- Pass D -----------------------------------------------------
// 1 block x 256 thr: sum nPart per-block partials -> d_out.
__global__ __launch_bounds__(256) void pass_d(
    const float* __restrict__ part, float* __restrict__ out, float invN, int n)
{
  __shared__ float red[4];
  int t = threadIdx.x, w = t >> 6, lane = t & 63;
  float s = 0.f;
  for (int i = t; i < n; i += 256) s += part[i];
  s += __shfl_xor(s, 1);  s += __shfl_xor(s, 2);  s += __shfl_xor(s, 4);
  s += __shfl_xor(s, 8);  s += __shfl_xor(s, 16); s += __shfl_xor(s, 32);
  if (lane == 0) red[w] = s;
  __syncthreads();
  if (t == 0) out[0] = (red[0] + red[1] + red[2] + red[3]) * invN;
}

extern "C" void kernel_launch(void* const* d_in, const int* in_sizes, int n_in,
                              void* d_out, int out_size, void* d_ws, size_t ws_size,
                              hipStream_t stream) {
  const float* emb = (const float*)d_in[0];
  const int* fam = (const int*)d_in[1];
  int N = in_sizes[0] / D_DIM;               // 262144
  int blocksA = N / 1024;                    // 256
  int blocksC = N / 128;                     // 2048

  // ws (float units): psum[256*8192] | protoRaw[8192] | protoB(8192 ushort)
  // | ehat[N*64 uint] | part[2048]
  float* ws = (float*)d_ws;
  float* psum = ws;
  size_t off = (size_t)blocksA * (F_NUM * D_DIM);
  float* protoRaw = ws + off;                off += F_NUM * D_DIM;
  unsigned short* protoB = (unsigned short*)(ws + off); off += (F_NUM * D_DIM) / 2;
  unsigned int* ehat = (unsigned int*)(ws + off);       off += (size_t)N * 64;
  float* part = ws + off;

  pass_a<<<blocksA, 1024, 0, stream>>>(emb, fam, psum, ehat);
  pass_b1<<<4 * F_NUM, 256, 0, stream>>>(psum, protoRaw, blocksA);
  pass_b2<<<1, 256, 0, stream>>>(protoRaw, protoB);
  pass_c<<<blocksC, 256, 0, stream>>>((const unsigned short*)ehat, fam, protoB, part);
  pass_d<<<1, 256, 0, stream>>>(part, (float*)d_out, 1.0f / (float)N, blocksC);
}

// Round 3
// 350.781 us; speedup vs baseline: 1.0733x; 1.0733x over previous
//
#include <hip/hip_runtime.h>
#include <math.h>

// ProtoLoss: loss = mean_n( -2*sim[n,fam[n]] + logsumexp_f(4*sim[n,f]) )
// sim = (e.p)/(||e||*||p||) -- scale-invariant in p: p_hat = raw_sum/||raw_sum||.
// N=262144, D=128, F=64.
//
// A) 256 blocks x 1024 thr. Lane (r=lane&15, c=lane>>4): 16 rows per wave
//    instruction, lane owns 32 contiguous dims (8 float4, ALL static indexing
//    -- r2's runtime-indexed scratch spill removed). Segment sum via
//    ds_add_f32 into 4 LDS replicas with slot(f,d)=f*132+c*33+k (d=32c+k):
//    bank=(4f+c+k)&31 -> the 4 quarter-lanes hit distinct banks, rows spread
//    by 4f -> ~2-way avg (free). No ehat write, no norm here.
// B) 64 blocks (one per family): reduce 256 partials + normalize -> protoB
//    bf16 (fused old B1+B2).
// C) swapped-operand MFMA: mfma(proto_frag, sample_frag) -> lane owns 16
//    f-values of its own sample => softmax reduce = VALU + 2 shfls (was 64
//    dependent shuffles). Reads emb fp32 directly (L3-warm), cvt bf16
//    in-register, ||e||^2 computed inline. part[bid] store (no atomic).
// D) 1-block reduce of 2048 partials -> d_out.

#define D_DIM 128
#define F_NUM 64
#define FPAD 132                        // LDS f-stride (floats): bank=(4f+c+k)&31
#define REP_STRIDE (F_NUM * FPAD)       // 8448 floats per replica

typedef __attribute__((ext_vector_type(8))) short short8;
typedef __attribute__((ext_vector_type(4))) float f32x4;

static __device__ __forceinline__ unsigned short f2bf(float x) {
  union { float f; unsigned u; } v; v.f = x;
  unsigned r = v.u + 0x7FFFu + ((v.u >> 16) & 1u);   // RNE
  return (unsigned short)(r >> 16);
}

// ---------------- Pass A -----------------------------------------------------
__global__ __launch_bounds__(1024) void pass_a(
    const float* __restrict__ emb, const int* __restrict__ fam,
    float* __restrict__ psum)
{
  __shared__ float acc[4 * REP_STRIDE];      // 135168 B (<= 160 KB)
  int t = threadIdx.x;
  for (int i = t; i < 4 * REP_STRIDE; i += 1024) acc[i] = 0.f;
  __syncthreads();

  int w = t >> 6, lane = t & 63;
  int r = lane & 15, c = lane >> 4;          // row-in-batch, dim-quarter
  float* rep = acc + (w & 3) * REP_STRIDE;
  int rowBase = blockIdx.x * 1024 + w * 64;

  #pragma unroll 2
  for (int b = 0; b < 4; ++b) {
    int row = rowBase + b * 16 + r;
    const float4* src = (const float4*)(emb + (size_t)row * D_DIM + c * 32);
    float4 v[8];
    #pragma unroll
    for (int i = 0; i < 8; ++i) v[i] = src[i];   // static idx: stays in VGPRs
    int f = fam[row];
    float* base = rep + f * FPAD + c * 33;       // element d=32c+k at base[k]
    #pragma unroll
    for (int i = 0; i < 8; ++i) {                // 32 ds_add, imm offsets 0..31
      unsafeAtomicAdd(&base[4 * i + 0], v[i].x);
      unsafeAtomicAdd(&base[4 * i + 1], v[i].y);
      unsafeAtomicAdd(&base[4 * i + 2], v[i].z);
      unsafeAtomicAdd(&base[4 * i + 3], v[i].w);
    }
  }
  __syncthreads();

  // merge 4 replicas, un-permute slots -> natural [f][128] psum slot
  float4* out4 = (float4*)(psum + (size_t)blockIdx.x * (F_NUM * D_DIM));
  #pragma unroll
  for (int k = 0; k < 2; ++k) {
    int i4 = t + k * 1024;                   // float4 id 0..2047
    int f = i4 >> 5, d0 = (i4 & 31) << 2;    // d0 in {0,4,...,124}
    int slot = f * FPAD + d0 + (d0 >> 5);    // slot(f,d)=f*132+d+(d>>5)
    float4 rs;
    rs.x = acc[slot + 0] + acc[slot + 0 + REP_STRIDE] +
           acc[slot + 0 + 2 * REP_STRIDE] + acc[slot + 0 + 3 * REP_STRIDE];
    rs.y = acc[slot + 1] + acc[slot + 1 + REP_STRIDE] +
           acc[slot + 1 + 2 * REP_STRIDE] + acc[slot + 1 + 3 * REP_STRIDE];
    rs.z = acc[slot + 2] + acc[slot + 2 + REP_STRIDE] +
           acc[slot + 2 + 2 * REP_STRIDE] + acc[slot + 2 + 3 * REP_STRIDE];
    rs.w = acc[slot + 3] + acc[slot + 3 + REP_STRIDE] +
           acc[slot + 3 + 2 * REP_STRIDE] + acc[slot + 3 + 3 * REP_STRIDE];
    out4[i4] = rs;
  }
}

// ---------------- Pass B (fused B1+B2) --------------------------------------
// 64 blocks x 256 thr. Block f: thread (d4=t&31, pg=t>>5) sums 32 partials of
// float4 d4; LDS combine 8 groups; lanes 0..31 normalize + write bf16 row.
__global__ __launch_bounds__(256) void pass_b(
    const float* __restrict__ psum, unsigned short* __restrict__ protoB,
    int nPart)
{
  __shared__ float4 sh[256];
  int t = threadIdx.x, f = blockIdx.x;
  int d4 = t & 31, pg = t >> 5;
  const float4* p4 = (const float4*)psum;    // partial stride 2048 float4
  float4 s = make_float4(0.f, 0.f, 0.f, 0.f);
  int per = nPart >> 3;                      // 32
  #pragma unroll 8
  for (int i = 0; i < per; ++i) {
    float4 a = p4[(size_t)(pg + 8 * i) * (F_NUM * D_DIM / 4) + f * 32 + d4];
    s.x += a.x; s.y += a.y; s.z += a.z; s.w += a.w;
  }
  sh[t] = s;
  __syncthreads();
  if (t < 32) {
    float4 rsum = sh[t];
    #pragma unroll
    for (int g = 1; g < 8; ++g) {
      float4 a = sh[g * 32 + t];
      rsum.x += a.x; rsum.y += a.y; rsum.z += a.z; rsum.w += a.w;
    }
    float n2 = rsum.x * rsum.x + rsum.y * rsum.y +
               rsum.z * rsum.z + rsum.w * rsum.w;
    n2 += __shfl_xor(n2, 1);  n2 += __shfl_xor(n2, 2);  n2 += __shfl_xor(n2, 4);
    n2 += __shfl_xor(n2, 8);  n2 += __shfl_xor(n2, 16);
    float inv = rsqrtf(fmaxf(n2, 1e-24f));   // empty family -> p_hat=0 -> sim=0
    ushort4 u;
    u.x = f2bf(rsum.x * inv); u.y = f2bf(rsum.y * inv);
    u.z = f2bf(rsum.z * inv); u.w = f2bf(rsum.w * inv);
    ((ushort4*)protoB)[f * 32 + t] = u;      // natural [f][128] bf16
  }
}

// ---------------- Pass C -----------------------------------------------------
// N/128 blocks x 256 thr. Wave handles 32 samples (2 st-tiles of 16).
// mfma(A=proto_frag, B=sample_frag): D[row = f-local q*4+reg][col = sample m16]
// => acc[st][ft][reg] = dot(proto ft*16+q*4+reg, e[S0+st*16+m16]).
__global__ __launch_bounds__(256) void pass_c(
    const float* __restrict__ emb, const int* __restrict__ fam,
    const unsigned short* __restrict__ protoB, float* __restrict__ part)
{
  __shared__ float sWp[4];
  int t = threadIdx.x, w = t >> 6, lane = t & 63;
  int m16 = lane & 15, q = lane >> 4;
  int S0 = blockIdx.x * 128 + w * 32;

  const float4* E4 = (const float4*)emb;     // row stride 32 float4
  const short8* P8 = (const short8*)protoB;  // row stride 16 chunks

  size_t e0 = (size_t)(S0 + m16) * 32 + q * 2;       // st=0
  size_t e1 = e0 + 16 * 32;                          // st=1
  int pb = m16 * 16 + q;                             // proto frag base (ft=0)

  f32x4 acc[2][4] = {};
  float s2a = 0.f, s2b = 0.f;

  #pragma unroll
  for (int ks = 0; ks < 4; ++ks) {
    short8 a0 = P8[pb + ks * 4];             // protos ft=0 (rows 0..15)
    short8 a1 = P8[pb + 256 + ks * 4];       // ft=1
    short8 a2 = P8[pb + 512 + ks * 4];       // ft=2
    short8 a3 = P8[pb + 768 + ks * 4];       // ft=3

    float4 va = E4[e0 + ks * 8], vb = E4[e0 + ks * 8 + 1];
    s2a += va.x * va.x + va.y * va.y + va.z * va.z + va.w * va.w +
           vb.x * vb.x + vb.y * vb.y + vb.z * vb.z + vb.w * vb.w;
    short8 b0;
    b0[0] = (short)f2bf(va.x); b0[1] = (short)f2bf(va.y);
    b0[2] = (short)f2bf(va.z); b0[3] = (short)f2bf(va.w);
    b0[4] = (short)f2bf(vb.x); b0[5] = (short)f2bf(vb.y);
    b0[6] = (short)f2bf(vb.z); b0[7] = (short)f2bf(vb.w);
    acc[0][0] = __builtin_amdgcn_mfma_f32_16x16x32_bf16(a0, b0, acc[0][0], 0, 0, 0);
    acc[0][1] = __builtin_amdgcn_mfma_f32_16x16x32_bf16(a1, b0, acc[0][1], 0, 0, 0);
    acc[0][2] = __builtin_amdgcn_mfma_f32_16x16x32_bf16(a2, b0, acc[0][2], 0, 0, 0);
    acc[0][3] = __builtin_amdgcn_mfma_f32_16x16x32_bf16(a3, b0, acc[0][3], 0, 0, 0);

    float4 vc = E4[e1 + ks * 8], vd = E4[e1 + ks * 8 + 1];
    s2b += vc.x * vc.x + vc.y * vc.y + vc.z * vc.z + vc.w * vc.w +
           vd.x * vd.x + vd.y * vd.y + vd.z * vd.z + vd.w * vd.w;
    short8 b1;
    b1[0] = (short)f2bf(vc.x); b1[1] = (short)f2bf(vc.y);
    b1[2] = (short)f2bf(vc.z); b1[3] = (short)f2bf(vc.w);
    b1[4] = (short)f2bf(vd.x); b1[5] = (short)f2bf(vd.y);
    b1[6] = (short)f2bf(vd.z); b1[7] = (short)f2bf(vd.w);
    acc[1][0] = __builtin_amdgcn_mfma_f32_16x16x32_bf16(a0, b1, acc[1][0], 0, 0, 0);
    acc[1][1] = __builtin_amdgcn_mfma_f32_16x16x32_bf16(a1, b1, acc[1][1], 0, 0, 0);
    acc[1][2] = __builtin_amdgcn_mfma_f32_16x16x32_bf16(a2, b1, acc[1][2], 0, 0, 0);
    acc[1][3] = __builtin_amdgcn_mfma_f32_16x16x32_bf16(a3, b1, acc[1][3], 0, 0, 0);
  }

  // per-sample norms: lane covers dims {ks*32+q*8..+8}; q-reduce completes 128
  s2a += __shfl_xor(s2a, 16); s2a += __shfl_xor(s2a, 32);
  s2b += __shfl_xor(s2b, 16); s2b += __shfl_xor(s2b, 32);
  float rn0 = rsqrtf(fmaxf(s2a, 1e-20f));
  float rn1 = rsqrtf(fmaxf(s2b, 1e-20f));
  int fr0 = fam[S0 + m16], fr1 = fam[S0 + 16 + m16];

  float wp = 0.f;
  {
    int fh = fr0 >> 4, fq = (fr0 >> 2) & 3, fl = fr0 & 3;
    float es = 0.f, ps = 0.f;
    #pragma unroll
    for (int ft = 0; ft < 4; ++ft)
      #pragma unroll
      for (int i = 0; i < 4; ++i) {
        float sim = acc[0][ft][i] * rn0;     // f = ft*16 + q*4 + i
        es += __expf(4.f * sim - 4.f);       // arg in [-8, ~0]
        ps += (fq == q && fh == ft && fl == i) ? sim : 0.f;
      }
    es += __shfl_xor(es, 16); es += __shfl_xor(es, 32);
    ps += __shfl_xor(ps, 16); ps += __shfl_xor(ps, 32);
    if (q == 0) wp += 4.f + __logf(es) - 2.f * ps;
  }
  {
    int fh = fr1 >> 4, fq = (fr1 >> 2) & 3, fl = fr1 & 3;
    float es = 0.f, ps = 0.f;
    #pragma unroll
    for (int ft = 0; ft < 4; ++ft)
      #pragma unroll
      for (int i = 0; i < 4; ++i) {
        float sim = acc[1][ft][i] * rn1;
        es += __expf(4.f * sim - 4.f);
        ps += (fq == q && fh == ft && fl == i) ? sim : 0.f;
      }
    es += __shfl_xor(es, 16); es += __shfl_xor(es, 32);
    ps += __shfl_xor(ps, 16); ps += __shfl_xor(ps, 32);
    if (q == 0) wp += 4.f + __logf(es) - 2.f * ps;
  }

  // wave total (q!=0 lanes hold 0)
  wp += __shfl_xor(wp, 1);  wp += __shfl_xor(wp, 2);  wp += __shfl_xor(wp, 4);
  wp += __shfl_xor(wp, 8);  wp += __shfl_xor(wp, 16); wp += __shfl_xor(wp, 32);
  if (lane == 0) sWp[w] = wp;
  __syncthreads();
  if (t == 0) part[blockIdx.x] = sWp[0] + sWp[1] + sWp[2] + sWp[3];
}

// ---------------- Pass D -----------------------------------------------------
__global__ __launch_bounds__(256) void pass_d(
    const float* __restrict__ part, float* __restrict__ out, float invN, int n)
{
  __shared__ float red[4];
  int t = threadIdx.x, w = t >> 6, lane = t & 63;
  float s = 0.f;
  for (int i = t; i < n; i += 256) s += part[i];
  s += __shfl_xor(s, 1);  s += __shfl_xor(s, 2);  s += __shfl_xor(s, 4);
  s += __shfl_xor(s, 8);  s += __shfl_xor(s, 16); s += __shfl_xor(s, 32);
  if (lane == 0) red[w] = s;
  __syncthreads();
  if (t == 0) out[0] = (red[0] + red[1] + red[2] + red[3]) * invN;
}

extern "C" void kernel_launch(void* const* d_in, const int* in_sizes, int n_in,
                              void* d_out, int out_size, void* d_ws, size_t ws_size,
                              hipStream_t stream) {
  const float* emb = (const float*)d_in[0];
  const int* fam = (const int*)d_in[1];
  int N = in_sizes[0] / D_DIM;               // 262144
  int blocksA = N / 1024;                    // 256
  int blocksC = N / 128;                     // 2048

  // ws (float units): psum[256*8192] | protoB(8192 ushort) | part[2048]
  float* ws = (float*)d_ws;
  float* psum = ws;
  size_t off = (size_t)blocksA * (F_NUM * D_DIM);
  unsigned short* protoB = (unsigned short*)(ws + off); off += (F_NUM * D_DIM) / 2;
  float* part = ws + off;

  pass_a<<<blocksA, 1024, 0, stream>>>(emb, fam, psum);
  pass_b<<<F_NUM, 256, 0, stream>>>(psum, protoB, blocksA);
  pass_c<<<blocksC, 256, 0, stream>>>(emb, fam, protoB, part);
  pass_d<<<1, 256, 0, stream>>>(part, (float*)d_out, 1.0f / (float)N, blocksC);
}

// Round 4
// 303.710 us; speedup vs baseline: 1.2397x; 1.1550x over previous
//
#include <hip/hip_runtime.h>
#include <math.h>

// ProtoLoss: loss = mean_n( -2*sim[n,fam[n]] + logsumexp_f(4*sim[n,f]) )
// sim = (e.p)/(||e||*||p||) -- scale-invariant in p: p_hat = raw_sum/||raw_sum||.
// N=262144, D=128, F=64.
//
// r3 post-mortem: LDS fp32 atomics measured ~0.3 lane-ops/cyc/CU (r1 196us,
// r3 175us, both 131072 lane-atomics/block; VALUBusy 0.6%, conflicts 0) --
// any per-element-atomic segment sum is floored at ~150us. Also: ~156us of
// the total is harness workspace-poison fills (2x78us, WRITE=512MB) inside
// the timed window; pass_b+c+d are only ~19us.
//
// A) segment sum AS MATMUL on the matrix cores: psum[f][d] = sum_r
//    onehot[f][r] * emb[r][d]. A-operand = one-hot (bf16-exact), B = emb
//    split hi/lo bf16 (hi = truncated, lo = RNE(x-hi)) -> fp32-exact to
//    ~2^-17. Zero atomics, zero LDS in the main loop. 256 blocks x 256 thr
//    (4 waves); wave = 256 rows = 8 steps of K=32. Per step: 8 fam dwords,
//    4 one-hot A-frags (cmp+sel), 8 dim-tiles x {8 dword gathers (one VGPR
//    addr + imm offsets, L1-friendly 64B granules), hi/lo cvt, 8 MFMA}.
//    Epilogue: 4 plain-write LDS replicas stride 129 (<=2-way banks), merge.
// B) 64 blocks: reduce 256 partials + normalize -> protoB bf16.
// C) swapped-operand MFMA sims + fused lse epilogue (unchanged, ~14us).
// D) 1-block reduce of 2048 partials -> d_out.

#define D_DIM 128
#define F_NUM 64
#define FPAD 129                        // LDS row stride (floats)
#define REP (F_NUM * FPAD)              // 8256 floats per wave replica

typedef __attribute__((ext_vector_type(8))) short short8;
typedef __attribute__((ext_vector_type(4))) float f32x4;

static __device__ __forceinline__ unsigned short f2bf(float x) {
  union { float f; unsigned u; } v; v.f = x;
  unsigned r = v.u + 0x7FFFu + ((v.u >> 16) & 1u);   // RNE
  return (unsigned short)(r >> 16);
}

// ---------------- Pass A -----------------------------------------------------
__global__ __launch_bounds__(256) void pass_a(
    const float* __restrict__ emb, const int* __restrict__ fam,
    float* __restrict__ psum)
{
  __shared__ float sAcc[4 * REP];            // 132096 B; no init needed
  int t = threadIdx.x, w = t >> 6, lane = t & 63;
  int m16 = lane & 15, q = lane >> 4;

  f32x4 acc[4][8] = {};                      // [f-tile][dim-tile], static idx
  int rb0 = blockIdx.x * 1024 + w * 256;

  #pragma unroll 1
  for (int s = 0; s < 8; ++s) {
    int rb = rb0 + s * 32;                   // K-slab of 32 rows
    // fam for this lane's k-slots: k = q*8 + j  (A-operand k mapping,
    // identical to r3 pass_c's verified convention)
    int fj[8];
    #pragma unroll
    for (int j = 0; j < 8; ++j) fj[j] = fam[rb + q * 8 + j];

    // one-hot A-frags: A[m16][k] = (fam[k] == ft*16+m16) ? 1.0bf16 : 0
    short8 af[4];
    #pragma unroll
    for (int ft = 0; ft < 4; ++ft) {
      #pragma unroll
      for (int j = 0; j < 8; ++j)
        af[ft][j] = (fj[j] == ft * 16 + m16) ? (short)0x3F80 : (short)0;
    }

    const float* eb = emb + (size_t)(rb + q * 8) * D_DIM + m16;
    #pragma unroll 2
    for (int nt = 0; nt < 8; ++nt) {
      float x[8];
      #pragma unroll
      for (int j = 0; j < 8; ++j)            // one addr VGPR + imm offsets
        x[j] = eb[j * D_DIM + nt * 16];
      short8 hf, lf;                         // hi = truncate, lo = RNE(x-hi)
      #pragma unroll
      for (int j = 0; j < 8; ++j) {
        unsigned bits = __float_as_uint(x[j]);
        hf[j] = (short)(bits >> 16);
        float lo = x[j] - __uint_as_float(bits & 0xFFFF0000u);
        lf[j] = (short)f2bf(lo);
      }
      #pragma unroll
      for (int ft = 0; ft < 4; ++ft) {
        acc[ft][nt] = __builtin_amdgcn_mfma_f32_16x16x32_bf16(af[ft], hf, acc[ft][nt], 0, 0, 0);
        acc[ft][nt] = __builtin_amdgcn_mfma_f32_16x16x32_bf16(af[ft], lf, acc[ft][nt], 0, 0, 0);
      }
    }
  }

  // wave replica: D[fam = ft*16+q*4+i][dim = nt*16+m16]; stride 129 -> 2-way
  float* rep = sAcc + w * REP;
  #pragma unroll
  for (int ft = 0; ft < 4; ++ft)
    #pragma unroll
    for (int nt = 0; nt < 8; ++nt)
      #pragma unroll
      for (int i = 0; i < 4; ++i)
        rep[(ft * 16 + q * 4 + i) * FPAD + nt * 16 + m16] = acc[ft][nt][i];
  __syncthreads();

  // merge 4 replicas -> natural [64][128] psum partial
  float* outp = psum + (size_t)blockIdx.x * (F_NUM * D_DIM);
  #pragma unroll
  for (int k = 0; k < 32; ++k) {
    int idx = t + k * 256;
    int f = idx >> 7, d = idx & 127;
    int slot = f * FPAD + d;
    outp[idx] = sAcc[slot] + sAcc[slot + REP] +
                sAcc[slot + 2 * REP] + sAcc[slot + 3 * REP];
  }
}

// ---------------- Pass B (fused reduce + normalize) --------------------------
// 64 blocks x 256 thr. Block f: thread (d4=t&31, pg=t>>5) sums 32 partials of
// float4 d4; LDS combine 8 groups; lanes 0..31 normalize + write bf16 row.
__global__ __launch_bounds__(256) void pass_b(
    const float* __restrict__ psum, unsigned short* __restrict__ protoB,
    int nPart)
{
  __shared__ float4 sh[256];
  int t = threadIdx.x, f = blockIdx.x;
  int d4 = t & 31, pg = t >> 5;
  const float4* p4 = (const float4*)psum;    // partial stride 2048 float4
  float4 s = make_float4(0.f, 0.f, 0.f, 0.f);
  int per = nPart >> 3;                      // 32
  #pragma unroll 8
  for (int i = 0; i < per; ++i) {
    float4 a = p4[(size_t)(pg + 8 * i) * (F_NUM * D_DIM / 4) + f * 32 + d4];
    s.x += a.x; s.y += a.y; s.z += a.z; s.w += a.w;
  }
  sh[t] = s;
  __syncthreads();
  if (t < 32) {
    float4 rsum = sh[t];
    #pragma unroll
    for (int g = 1; g < 8; ++g) {
      float4 a = sh[g * 32 + t];
      rsum.x += a.x; rsum.y += a.y; rsum.z += a.z; rsum.w += a.w;
    }
    float n2 = rsum.x * rsum.x + rsum.y * rsum.y +
               rsum.z * rsum.z + rsum.w * rsum.w;
    n2 += __shfl_xor(n2, 1);  n2 += __shfl_xor(n2, 2);  n2 += __shfl_xor(n2, 4);
    n2 += __shfl_xor(n2, 8);  n2 += __shfl_xor(n2, 16);
    float inv = rsqrtf(fmaxf(n2, 1e-24f));   // empty family -> p_hat=0 -> sim=0
    ushort4 u;
    u.x = f2bf(rsum.x * inv); u.y = f2bf(rsum.y * inv);
    u.z = f2bf(rsum.z * inv); u.w = f2bf(rsum.w * inv);
    ((ushort4*)protoB)[f * 32 + t] = u;      // natural [f][128] bf16
  }
}

// ---------------- Pass C -----------------------------------------------------
// N/128 blocks x 256 thr. Wave handles 32 samples (2 st-tiles of 16).
// mfma(A=proto_frag, B=sample_frag): D[f-local q*4+reg][sample m16].
__global__ __launch_bounds__(256) void pass_c(
    const float* __restrict__ emb, const int* __restrict__ fam,
    const unsigned short* __restrict__ protoB, float* __restrict__ part)
{
  __shared__ float sWp[4];
  int t = threadIdx.x, w = t >> 6, lane = t & 63;
  int m16 = lane & 15, q = lane >> 4;
  int S0 = blockIdx.x * 128 + w * 32;

  const float4* E4 = (const float4*)emb;     // row stride 32 float4
  const short8* P8 = (const short8*)protoB;  // row stride 16 chunks

  size_t e0 = (size_t)(S0 + m16) * 32 + q * 2;       // st=0
  size_t e1 = e0 + 16 * 32;                          // st=1
  int pb = m16 * 16 + q;                             // proto frag base (ft=0)

  f32x4 acc[2][4] = {};
  float s2a = 0.f, s2b = 0.f;

  #pragma unroll
  for (int ks = 0; ks < 4; ++ks) {
    short8 a0 = P8[pb + ks * 4];             // protos ft=0 (rows 0..15)
    short8 a1 = P8[pb + 256 + ks * 4];       // ft=1
    short8 a2 = P8[pb + 512 + ks * 4];       // ft=2
    short8 a3 = P8[pb + 768 + ks * 4];       // ft=3

    float4 va = E4[e0 + ks * 8], vb = E4[e0 + ks * 8 + 1];
    s2a += va.x * va.x + va.y * va.y + va.z * va.z + va.w * va.w +
           vb.x * vb.x + vb.y * vb.y + vb.z * vb.z + vb.w * vb.w;
    short8 b0;
    b0[0] = (short)f2bf(va.x); b0[1] = (short)f2bf(va.y);
    b0[2] = (short)f2bf(va.z); b0[3] = (short)f2bf(va.w);
    b0[4] = (short)f2bf(vb.x); b0[5] = (short)f2bf(vb.y);
    b0[6] = (short)f2bf(vb.z); b0[7] = (short)f2bf(vb.w);
    acc[0][0] = __builtin_amdgcn_mfma_f32_16x16x32_bf16(a0, b0, acc[0][0], 0, 0, 0);
    acc[0][1] = __builtin_amdgcn_mfma_f32_16x16x32_bf16(a1, b0, acc[0][1], 0, 0, 0);
    acc[0][2] = __builtin_amdgcn_mfma_f32_16x16x32_bf16(a2, b0, acc[0][2], 0, 0, 0);
    acc[0][3] = __builtin_amdgcn_mfma_f32_16x16x32_bf16(a3, b0, acc[0][3], 0, 0, 0);

    float4 vc = E4[e1 + ks * 8], vd = E4[e1 + ks * 8 + 1];
    s2b += vc.x * vc.x + vc.y * vc.y + vc.z * vc.z + vc.w * vc.w +
           vd.x * vd.x + vd.y * vd.y + vd.z * vd.z + vd.w * vd.w;
    short8 b1;
    b1[0] = (short)f2bf(vc.x); b1[1] = (short)f2bf(vc.y);
    b1[2] = (short)f2bf(vc.z); b1[3] = (short)f2bf(vc.w);
    b1[4] = (short)f2bf(vd.x); b1[5] = (short)f2bf(vd.y);
    b1[6] = (short)f2bf(vd.z); b1[7] = (short)f2bf(vd.w);
    acc[1][0] = __builtin_amdgcn_mfma_f32_16x16x32_bf16(a0, b1, acc[1][0], 0, 0, 0);
    acc[1][1] = __builtin_amdgcn_mfma_f32_16x16x32_bf16(a1, b1, acc[1][1], 0, 0, 0);
    acc[1][2] = __builtin_amdgcn_mfma_f32_16x16x32_bf16(a2, b1, acc[1][2], 0, 0, 0);
    acc[1][3] = __builtin_amdgcn_mfma_f32_16x16x32_bf16(a3, b1, acc[1][3], 0, 0, 0);
  }

  // per-sample norms: lane covers dims {ks*32+q*8..+8}; q-reduce completes 128
  s2a += __shfl_xor(s2a, 16); s2a += __shfl_xor(s2a, 32);
  s2b += __shfl_xor(s2b, 16); s2b += __shfl_xor(s2b, 32);
  float rn0 = rsqrtf(fmaxf(s2a, 1e-20f));
  float rn1 = rsqrtf(fmaxf(s2b, 1e-20f));
  int fr0 = fam[S0 + m16], fr1 = fam[S0 + 16 + m16];

  float wp = 0.f;
  {
    int fh = fr0 >> 4, fq = (fr0 >> 2) & 3, fl = fr0 & 3;
    float es = 0.f, ps = 0.f;
    #pragma unroll
    for (int ft = 0; ft < 4; ++ft)
      #pragma unroll
      for (int i = 0; i < 4; ++i) {
        float sim = acc[0][ft][i] * rn0;     // f = ft*16 + q*4 + i
        es += __expf(4.f * sim - 4.f);       // arg in [-8, ~0]
        ps += (fq == q && fh == ft && fl == i) ? sim : 0.f;
      }
    es += __shfl_xor(es, 16); es += __shfl_xor(es, 32);
    ps += __shfl_xor(ps, 16); ps += __shfl_xor(ps, 32);
    if (q == 0) wp += 4.f + __logf(es) - 2.f * ps;
  }
  {
    int fh = fr1 >> 4, fq = (fr1 >> 2) & 3, fl = fr1 & 3;
    float es = 0.f, ps = 0.f;
    #pragma unroll
    for (int ft = 0; ft < 4; ++ft)
      #pragma unroll
      for (int i = 0; i < 4; ++i) {
        float sim = acc[1][ft][i] * rn1;
        es += __expf(4.f * sim - 4.f);
        ps += (fq == q && fh == ft && fl == i) ? sim : 0.f;
      }
    es += __shfl_xor(es, 16); es += __shfl_xor(es, 32);
    ps += __shfl_xor(ps, 16); ps += __shfl_xor(ps, 32);
    if (q == 0) wp += 4.f + __logf(es) - 2.f * ps;
  }

  // wave total (q!=0 lanes hold 0)
  wp += __shfl_xor(wp, 1);  wp += __shfl_xor(wp, 2);  wp += __shfl_xor(wp, 4);
  wp += __shfl_xor(wp, 8);  wp += __shfl_xor(wp, 16); wp += __shfl_xor(wp, 32);
  if (lane == 0) sWp[w] = wp;
  __syncthreads();
  if (t == 0) part[blockIdx.x] = sWp[0] + sWp[1] + sWp[2] + sWp[3];
}

// ---------------- Pass D -----------------------------------------------------
__global__ __launch_bounds__(256) void pass_d(
    const float* __restrict__ part, float* __restrict__ out, float invN, int n)
{
  __shared__ float red[4];
  int t = threadIdx.x, w = t >> 6, lane = t & 63;
  float s = 0.f;
  for (int i = t; i < n; i += 256) s += part[i];
  s += __shfl_xor(s, 1);  s += __shfl_xor(s, 2);  s += __shfl_xor(s, 4);
  s += __shfl_xor(s, 8);  s += __shfl_xor(s, 16); s += __shfl_xor(s, 32);
  if (lane == 0) red[w] = s;
  __syncthreads();
  if (t == 0) out[0] = (red[0] + red[1] + red[2] + red[3]) * invN;
}

extern "C" void kernel_launch(void* const* d_in, const int* in_sizes, int n_in,
                              void* d_out, int out_size, void* d_ws, size_t ws_size,
                              hipStream_t stream) {
  const float* emb = (const float*)d_in[0];
  const int* fam = (const int*)d_in[1];
  int N = in_sizes[0] / D_DIM;               // 262144
  int blocksA = N / 1024;                    // 256
  int blocksC = N / 128;                     // 2048

  // ws (float units): psum[256*8192] | protoB(8192 ushort) | part[2048]
  float* ws = (float*)d_ws;
  float* psum = ws;
  size_t off = (size_t)blocksA * (F_NUM * D_DIM);
  unsigned short* protoB = (unsigned short*)(ws + off); off += (F_NUM * D_DIM) / 2;
  float* part = ws + off;

  pass_a<<<blocksA, 256, 0, stream>>>(emb, fam, psum);
  pass_b<<<F_NUM, 256, 0, stream>>>(psum, protoB, blocksA);
  pass_c<<<blocksC, 256, 0, stream>>>(emb, fam, protoB, part);
  pass_d<<<1, 256, 0, stream>>>(part, (float*)d_out, 1.0f / (float)N, blocksC);
}

// Round 5
// 235.102 us; speedup vs baseline: 1.6014x; 1.2918x over previous
//
#include <hip/hip_runtime.h>
#include <math.h>

// ProtoLoss: loss = mean_n( -2*sim[n,fam[n]] + logsumexp_f(4*sim[n,f]) )
// sim = (e.p)/(||e||*||p||) -- scale-invariant in p: p_hat = raw_sum/||raw_sum||.
// N=262144, D=128, F=64.
//
// r4 post-mortem: segment-sum-as-MFMA is right (absmax 0.0) but acc[4][8]
// = 128 VGPRs of accumulator spilled to scratch at VGPR_Count=132 -->
// WRITE_SIZE 301MB (vs 8 algorithmic), ~90us of scratch traffic.
//
// A) same math, dims split ACROSS WAVES: wave w owns dim-slice [32w,32w+32)
//    for ALL the block's rows -> acc[4 ft][2 nt] = 32 VGPRs, register-
//    resident. Slices disjoint -> no LDS, no barrier, direct reg->psum
//    stores. 512 blocks x 512 rows (2 blk/CU, 2 waves/SIMD). Per K-slab of
//    32 rows: 8 fam dwords, 4 one-hot A-frags (bf16-exact), 16 emb dword
//    gathers (64B segments, full-line utilization), hi/lo bf16 split
//    (hi=trunc, lo=RNE(x-hi), fp32-exact to ~2^-17), 16 MFMA.
// B) 64 blocks: reduce 512 partials + normalize -> protoB bf16.
// C) swapped-operand MFMA sims + fused lse epilogue (verified, ~14us).
// D) 1-block reduce of 2048 partials -> d_out.
//
// Known harness floor: two 512MB workspace poison-fills (~2x78us) sit inside
// the timed window; pass_b+c+d ~19us total.

#define D_DIM 128
#define F_NUM 64
#define ROWS_A 512

typedef __attribute__((ext_vector_type(8))) short short8;
typedef __attribute__((ext_vector_type(4))) float f32x4;

static __device__ __forceinline__ unsigned short f2bf(float x) {
  union { float f; unsigned u; } v; v.f = x;
  unsigned r = v.u + 0x7FFFu + ((v.u >> 16) & 1u);   // RNE
  return (unsigned short)(r >> 16);
}

// ---------------- Pass A -----------------------------------------------------
__global__ __launch_bounds__(256, 2) void pass_a(
    const float* __restrict__ emb, const int* __restrict__ fam,
    float* __restrict__ psum)
{
  int t = threadIdx.x, w = t >> 6, lane = t & 63;
  int m16 = lane & 15, q = lane >> 4;
  int dimBase = w * 32;                      // wave's private dim slice

  f32x4 acc[4][2] = {};                      // [f-tile][dim-tile] = 32 VGPRs
  int rb0 = blockIdx.x * ROWS_A;

  #pragma unroll 2
  for (int s = 0; s < ROWS_A / 32; ++s) {
    int rb = rb0 + s * 32;                   // K-slab of 32 rows
    // fam for this lane's k-slots: k = q*8 + j (r4-verified A convention)
    const int* fp = fam + rb + q * 8;
    int fj[8];
    #pragma unroll
    for (int j = 0; j < 8; ++j) fj[j] = fp[j];

    // B-operand: lane m16 = dim, k = q*8+j (r4-verified). One addr VGPR,
    // imm offsets; 16 lanes x 4B = contiguous 64B segments.
    const float* eb = emb + (size_t)(rb + q * 8) * D_DIM + dimBase + m16;
    float x0[8], x1[8];
    #pragma unroll
    for (int j = 0; j < 8; ++j) {
      x0[j] = eb[j * D_DIM];                 // nt=0: dims dimBase+m16
      x1[j] = eb[j * D_DIM + 16];            // nt=1: dims dimBase+16+m16
    }

    // one-hot A-frags: A[m16][k] = (fam[k] == ft*16+m16) ? 1.0bf16 : 0
    short8 af[4];
    #pragma unroll
    for (int ft = 0; ft < 4; ++ft)
      #pragma unroll
      for (int j = 0; j < 8; ++j)
        af[ft][j] = (fj[j] == ft * 16 + m16) ? (short)0x3F80 : (short)0;

    short8 h0, l0, h1, l1;                   // hi = truncate, lo = RNE(x-hi)
    #pragma unroll
    for (int j = 0; j < 8; ++j) {
      unsigned b0 = __float_as_uint(x0[j]);
      h0[j] = (short)(b0 >> 16);
      l0[j] = (short)f2bf(x0[j] - __uint_as_float(b0 & 0xFFFF0000u));
      unsigned b1 = __float_as_uint(x1[j]);
      h1[j] = (short)(b1 >> 16);
      l1[j] = (short)f2bf(x1[j] - __uint_as_float(b1 & 0xFFFF0000u));
    }

    #pragma unroll
    for (int ft = 0; ft < 4; ++ft) {
      acc[ft][0] = __builtin_amdgcn_mfma_f32_16x16x32_bf16(af[ft], h0, acc[ft][0], 0, 0, 0);
      acc[ft][0] = __builtin_amdgcn_mfma_f32_16x16x32_bf16(af[ft], l0, acc[ft][0], 0, 0, 0);
      acc[ft][1] = __builtin_amdgcn_mfma_f32_16x16x32_bf16(af[ft], h1, acc[ft][1], 0, 0, 0);
      acc[ft][1] = __builtin_amdgcn_mfma_f32_16x16x32_bf16(af[ft], l1, acc[ft][1], 0, 0, 0);
    }
  }

  // D[fam = ft*16+q*4+i][dim = dimBase+nt*16+m16]; direct reg->global,
  // 16-lane groups write contiguous 64B. All static indexing.
  float* outp = psum + (size_t)blockIdx.x * (F_NUM * D_DIM) + dimBase + m16;
  #pragma unroll
  for (int ft = 0; ft < 4; ++ft)
    #pragma unroll
    for (int i = 0; i < 4; ++i) {
      int f = ft * 16 + q * 4 + i;
      outp[(size_t)f * D_DIM]      = acc[ft][0][i];
      outp[(size_t)f * D_DIM + 16] = acc[ft][1][i];
    }
}

// ---------------- Pass B (fused reduce + normalize) --------------------------
// 64 blocks x 256 thr. Block f: thread (d4=t&31, pg=t>>5) sums 64 partials of
// float4 d4; LDS combine 8 groups; lanes 0..31 normalize + write bf16 row.
__global__ __launch_bounds__(256) void pass_b(
    const float* __restrict__ psum, unsigned short* __restrict__ protoB,
    int nPart)
{
  __shared__ float4 sh[256];
  int t = threadIdx.x, f = blockIdx.x;
  int d4 = t & 31, pg = t >> 5;
  const float4* p4 = (const float4*)psum;    // partial stride 2048 float4
  float4 s = make_float4(0.f, 0.f, 0.f, 0.f);
  int per = nPart >> 3;                      // 64
  #pragma unroll 8
  for (int i = 0; i < per; ++i) {
    float4 a = p4[(size_t)(pg + 8 * i) * (F_NUM * D_DIM / 4) + f * 32 + d4];
    s.x += a.x; s.y += a.y; s.z += a.z; s.w += a.w;
  }
  sh[t] = s;
  __syncthreads();
  if (t < 32) {
    float4 rsum = sh[t];
    #pragma unroll
    for (int g = 1; g < 8; ++g) {
      float4 a = sh[g * 32 + t];
      rsum.x += a.x; rsum.y += a.y; rsum.z += a.z; rsum.w += a.w;
    }
    float n2 = rsum.x * rsum.x + rsum.y * rsum.y +
               rsum.z * rsum.z + rsum.w * rsum.w;
    n2 += __shfl_xor(n2, 1);  n2 += __shfl_xor(n2, 2);  n2 += __shfl_xor(n2, 4);
    n2 += __shfl_xor(n2, 8);  n2 += __shfl_xor(n2, 16);
    float inv = rsqrtf(fmaxf(n2, 1e-24f));   // empty family -> p_hat=0 -> sim=0
    ushort4 u;
    u.x = f2bf(rsum.x * inv); u.y = f2bf(rsum.y * inv);
    u.z = f2bf(rsum.z * inv); u.w = f2bf(rsum.w * inv);
    ((ushort4*)protoB)[f * 32 + t] = u;      // natural [f][128] bf16
  }
}

// ---------------- Pass C -----------------------------------------------------
// N/128 blocks x 256 thr. Wave handles 32 samples (2 st-tiles of 16).
// mfma(A=proto_frag, B=sample_frag): D[f-local q*4+reg][sample m16].
__global__ __launch_bounds__(256) void pass_c(
    const float* __restrict__ emb, const int* __restrict__ fam,
    const unsigned short* __restrict__ protoB, float* __restrict__ part)
{
  __shared__ float sWp[4];
  int t = threadIdx.x, w = t >> 6, lane = t & 63;
  int m16 = lane & 15, q = lane >> 4;
  int S0 = blockIdx.x * 128 + w * 32;

  const float4* E4 = (const float4*)emb;     // row stride 32 float4
  const short8* P8 = (const short8*)protoB;  // row stride 16 chunks

  size_t e0 = (size_t)(S0 + m16) * 32 + q * 2;       // st=0
  size_t e1 = e0 + 16 * 32;                          // st=1
  int pb = m16 * 16 + q;                             // proto frag base (ft=0)

  f32x4 acc[2][4] = {};
  float s2a = 0.f, s2b = 0.f;

  #pragma unroll
  for (int ks = 0; ks < 4; ++ks) {
    short8 a0 = P8[pb + ks * 4];             // protos ft=0 (rows 0..15)
    short8 a1 = P8[pb + 256 + ks * 4];       // ft=1
    short8 a2 = P8[pb + 512 + ks * 4];       // ft=2
    short8 a3 = P8[pb + 768 + ks * 4];       // ft=3

    float4 va = E4[e0 + ks * 8], vb = E4[e0 + ks * 8 + 1];
    s2a += va.x * va.x + va.y * va.y + va.z * va.z + va.w * va.w +
           vb.x * vb.x + vb.y * vb.y + vb.z * vb.z + vb.w * vb.w;
    short8 b0;
    b0[0] = (short)f2bf(va.x); b0[1] = (short)f2bf(va.y);
    b0[2] = (short)f2bf(va.z); b0[3] = (short)f2bf(va.w);
    b0[4] = (short)f2bf(vb.x); b0[5] = (short)f2bf(vb.y);
    b0[6] = (short)f2bf(vb.z); b0[7] = (short)f2bf(vb.w);
    acc[0][0] = __builtin_amdgcn_mfma_f32_16x16x32_bf16(a0, b0, acc[0][0], 0, 0, 0);
    acc[0][1] = __builtin_amdgcn_mfma_f32_16x16x32_bf16(a1, b0, acc[0][1], 0, 0, 0);
    acc[0][2] = __builtin_amdgcn_mfma_f32_16x16x32_bf16(a2, b0, acc[0][2], 0, 0, 0);
    acc[0][3] = __builtin_amdgcn_mfma_f32_16x16x32_bf16(a3, b0, acc[0][3], 0, 0, 0);

    float4 vc = E4[e1 + ks * 8], vd = E4[e1 + ks * 8 + 1];
    s2b += vc.x * vc.x + vc.y * vc.y + vc.z * vc.z + vc.w * vc.w +
           vd.x * vd.x + vd.y * vd.y + vd.z * vd.z + vd.w * vd.w;
    short8 b1;
    b1[0] = (short)f2bf(vc.x); b1[1] = (short)f2bf(vc.y);
    b1[2] = (short)f2bf(vc.z); b1[3] = (short)f2bf(vc.w);
    b1[4] = (short)f2bf(vd.x); b1[5] = (short)f2bf(vd.y);
    b1[6] = (short)f2bf(vd.z); b1[7] = (short)f2bf(vd.w);
    acc[1][0] = __builtin_amdgcn_mfma_f32_16x16x32_bf16(a0, b1, acc[1][0], 0, 0, 0);
    acc[1][1] = __builtin_amdgcn_mfma_f32_16x16x32_bf16(a1, b1, acc[1][1], 0, 0, 0);
    acc[1][2] = __builtin_amdgcn_mfma_f32_16x16x32_bf16(a2, b1, acc[1][2], 0, 0, 0);
    acc[1][3] = __builtin_amdgcn_mfma_f32_16x16x32_bf16(a3, b1, acc[1][3], 0, 0, 0);
  }

  // per-sample norms: lane covers dims {ks*32+q*8..+8}; q-reduce completes 128
  s2a += __shfl_xor(s2a, 16); s2a += __shfl_xor(s2a, 32);
  s2b += __shfl_xor(s2b, 16); s2b += __shfl_xor(s2b, 32);
  float rn0 = rsqrtf(fmaxf(s2a, 1e-20f));
  float rn1 = rsqrtf(fmaxf(s2b, 1e-20f));
  int fr0 = fam[S0 + m16], fr1 = fam[S0 + 16 + m16];

  float wp = 0.f;
  {
    int fh = fr0 >> 4, fq = (fr0 >> 2) & 3, fl = fr0 & 3;
    float es = 0.f, ps = 0.f;
    #pragma unroll
    for (int ft = 0; ft < 4; ++ft)
      #pragma unroll
      for (int i = 0; i < 4; ++i) {
        float sim = acc[0][ft][i] * rn0;     // f = ft*16 + q*4 + i
        es += __expf(4.f * sim - 4.f);       // arg in [-8, ~0]
        ps += (fq == q && fh == ft && fl == i) ? sim : 0.f;
      }
    es += __shfl_xor(es, 16); es += __shfl_xor(es, 32);
    ps += __shfl_xor(ps, 16); ps += __shfl_xor(ps, 32);
    if (q == 0) wp += 4.f + __logf(es) - 2.f * ps;
  }
  {
    int fh = fr1 >> 4, fq = (fr1 >> 2) & 3, fl = fr1 & 3;
    float es = 0.f, ps = 0.f;
    #pragma unroll
    for (int ft = 0; ft < 4; ++ft)
      #pragma unroll
      for (int i = 0; i < 4; ++i) {
        float sim = acc[1][ft][i] * rn1;
        es += __expf(4.f * sim - 4.f);
        ps += (fq == q && fh == ft && fl == i) ? sim : 0.f;
      }
    es += __shfl_xor(es, 16); es += __shfl_xor(es, 32);
    ps += __shfl_xor(ps, 16); ps += __shfl_xor(ps, 32);
    if (q == 0) wp += 4.f + __logf(es) - 2.f * ps;
  }

  // wave total (q!=0 lanes hold 0)
  wp += __shfl_xor(wp, 1);  wp += __shfl_xor(wp, 2);  wp += __shfl_xor(wp, 4);
  wp += __shfl_xor(wp, 8);  wp += __shfl_xor(wp, 16); wp += __shfl_xor(wp, 32);
  if (lane == 0) sWp[w] = wp;
  __syncthreads();
  if (t == 0) part[blockIdx.x] = sWp[0] + sWp[1] + sWp[2] + sWp[3];
}

// ---------------- Pass D -----------------------------------------------------
__global__ __launch_bounds__(256) void pass_d(
    const float* __restrict__ part, float* __restrict__ out, float invN, int n)
{
  __shared__ float red[4];
  int t = threadIdx.x, w = t >> 6, lane = t & 63;
  float s = 0.f;
  for (int i = t; i < n; i += 256) s += part[i];
  s += __shfl_xor(s, 1);  s += __shfl_xor(s, 2);  s += __shfl_xor(s, 4);
  s += __shfl_xor(s, 8);  s += __shfl_xor(s, 16); s += __shfl_xor(s, 32);
  if (lane == 0) red[w] = s;
  __syncthreads();
  if (t == 0) out[0] = (red[0] + red[1] + red[2] + red[3]) * invN;
}

extern "C" void kernel_launch(void* const* d_in, const int* in_sizes, int n_in,
                              void* d_out, int out_size, void* d_ws, size_t ws_size,
                              hipStream_t stream) {
  const float* emb = (const float*)d_in[0];
  const int* fam = (const int*)d_in[1];
  int N = in_sizes[0] / D_DIM;               // 262144
  int blocksA = N / ROWS_A;                  // 512
  int blocksC = N / 128;                     // 2048

  // ws (float units): psum[512*8192] | protoB(8192 ushort) | part[2048]
  float* ws = (float*)d_ws;
  float* psum = ws;
  size_t off = (size_t)blocksA * (F_NUM * D_DIM);
  unsigned short* protoB = (unsigned short*)(ws + off); off += (F_NUM * D_DIM) / 2;
  float* part = ws + off;

  pass_a<<<blocksA, 256, 0, stream>>>(emb, fam, psum);
  pass_b<<<F_NUM, 256, 0, stream>>>(psum, protoB, blocksA);
  pass_c<<<blocksC, 256, 0, stream>>>(emb, fam, protoB, part);
  pass_d<<<1, 256, 0, stream>>>(part, (float*)d_out, 1.0f / (float)N, blocksC);
}